// Round 1
// baseline (376.557 us; speedup 1.0000x reference)
//
#include <hip/hip_runtime.h>

#define N_AGENTS 8192
#define FDIM 128
#define PDIM 16
#define NEDGES 262144

// ---------------------------------------------------------------- zero fill
__global__ void zero_out_k(float4* __restrict__ out, int n4) {
    int i = blockIdx.x * blockDim.x + threadIdx.x;
    int stride = gridDim.x * blockDim.x;
    float4 z = make_float4(0.f, 0.f, 0.f, 0.f);
    for (; i < n4; i += stride) out[i] = z;
}

// ------------------------------------------------- per-row precompute (1 wave/row)
// diff = feature - next_feature
// nf   = row-L2-normalized next_feature  (double-normalize is idempotent)
// arow/brow/grow = persona_t @ {alpha,beta,gamma}
__global__ void row_prep_k(const float* __restrict__ feature,
                           const float* __restrict__ next_feature,
                           const float* __restrict__ persona,
                           const float* __restrict__ alpha,
                           const float* __restrict__ beta,
                           const float* __restrict__ gamma,
                           float* __restrict__ diff,
                           float* __restrict__ nf,
                           float* __restrict__ arow,
                           float* __restrict__ brow,
                           float* __restrict__ grow) {
    int row  = (blockIdx.x * blockDim.x + threadIdx.x) >> 6;   // one wave64 per row
    int lane = threadIdx.x & 63;
    if (row >= N_AGENTS) return;

    const float2* f2 = (const float2*)(feature      + (size_t)row * FDIM);
    const float2* n2 = (const float2*)(next_feature + (size_t)row * FDIM);
    float2 f  = f2[lane];          // 64 lanes x float2 = 128 floats
    float2 nx = n2[lane];

    float2 d = make_float2(f.x - nx.x, f.y - nx.y);
    ((float2*)(diff + (size_t)row * FDIM))[lane] = d;

    float ss = nx.x * nx.x + nx.y * nx.y;

    float pa = 0.f, pb = 0.f, pg = 0.f;
    if (lane < PDIM) {
        float p = persona[(size_t)row * PDIM + lane];
        pa = p * alpha[lane];
        pb = p * beta[lane];
        pg = p * gamma[lane];
    }

    #pragma unroll
    for (int off = 32; off > 0; off >>= 1) {
        ss += __shfl_xor(ss, off);
        pa += __shfl_xor(pa, off);
        pb += __shfl_xor(pb, off);
        pg += __shfl_xor(pg, off);
    }

    float inv = 1.0f / sqrtf(ss);  // match ref: x / sqrt(sum(x^2))
    ((float2*)(nf + (size_t)row * FDIM))[lane] = make_float2(nx.x * inv, nx.y * inv);

    if (lane == 0) {
        arow[row] = pa;
        brow[row] = pb;
        grow[row] = pg;
    }
}

// ------------------------------------------------- act edges: 16 lanes / edge
__global__ void act_edges_k(const int* __restrict__ asrc,
                            const int* __restrict__ adst,
                            const float* __restrict__ diff,
                            const float* __restrict__ nf,
                            const float* __restrict__ arow,
                            const float* __restrict__ grow,
                            float* __restrict__ out) {
    int gid = blockIdx.x * blockDim.x + threadIdx.x;
    int e   = gid >> 4;          // 16 lanes per edge
    int sub = gid & 15;
    if (e >= NEDGES) return;

    int s = asrc[e];
    int d = adst[e];

    const float4* ds = (const float4*)(diff + (size_t)s * FDIM);
    const float4* dd = (const float4*)(diff + (size_t)d * FDIM);
    const float4* ns = (const float4*)(nf   + (size_t)s * FDIM);
    const float4* nd = (const float4*)(nf   + (size_t)d * FDIM);

    float imp = 0.f, sim = 0.f;
    #pragma unroll
    for (int k = 0; k < 2; ++k) {
        int idx = sub + k * 16;                 // 32 float4 per row, 16 lanes -> 2 each
        float4 a = ds[idx], b = dd[idx];
        imp += a.x * b.x + a.y * b.y + a.z * b.z + a.w * b.w;
        float4 c = ns[idx], g = nd[idx];
        sim += c.x * g.x + c.y * g.y + c.z * g.z + c.w * g.w;
    }

    #pragma unroll
    for (int off = 8; off > 0; off >>= 1) {
        imp += __shfl_xor(imp, off, 16);
        sim += __shfl_xor(sim, off, 16);
    }

    if (sub == 0) {
        float val = sim * arow[s] + imp * (1.0f / FDIM) * grow[s];
        atomicAdd(out + (size_t)s * N_AGENTS + d, val);
    }
}

// ------------------------------------------------- cost edges: 1 thread / edge
__global__ void cost_edges_k(const int* __restrict__ esrc,
                             const int* __restrict__ edst,
                             const float* __restrict__ brow,
                             float* __restrict__ out) {
    int e = blockIdx.x * blockDim.x + threadIdx.x;
    if (e >= NEDGES) return;
    int s = esrc[e];
    atomicAdd(out + (size_t)s * N_AGENTS + edst[e], -brow[s]);
}

// ---------------------------------------------------------------- launcher
extern "C" void kernel_launch(void* const* d_in, const int* in_sizes, int n_in,
                              void* d_out, int out_size, void* d_ws, size_t ws_size,
                              hipStream_t stream) {
    const float* feature      = (const float*)d_in[0];
    const float* next_feature = (const float*)d_in[1];
    const float* persona      = (const float*)d_in[2];
    const float* alpha        = (const float*)d_in[3];
    const float* beta         = (const float*)d_in[4];
    const float* gamma        = (const float*)d_in[5];
    const int*   act_src      = (const int*)d_in[6];
    const int*   act_dst      = (const int*)d_in[7];
    const int*   edge_src     = (const int*)d_in[8];
    const int*   edge_dst     = (const int*)d_in[9];

    float* out = (float*)d_out;

    // workspace layout (floats): diff[N*F] | nf[N*F] | arow[N] | brow[N] | grow[N]
    float* ws   = (float*)d_ws;
    float* diff = ws;
    float* nf   = diff + (size_t)N_AGENTS * FDIM;
    float* arow = nf   + (size_t)N_AGENTS * FDIM;
    float* brow = arow + N_AGENTS;
    float* grow = brow + N_AGENTS;

    // 1) zero the 8192x8192 output (poisoned to 0xAA each call)
    int n4 = (N_AGENTS * N_AGENTS) / 4;  // 16,777,216 float4
    zero_out_k<<<4096, 256, 0, stream>>>((float4*)out, n4);

    // 2) per-row precompute: 4 waves/block -> 4 rows/block
    row_prep_k<<<N_AGENTS / 4, 256, 0, stream>>>(
        feature, next_feature, persona, alpha, beta, gamma,
        diff, nf, arow, brow, grow);

    // 3) act-edge scatter (sim + impact)
    act_edges_k<<<(NEDGES * 16) / 256, 256, 0, stream>>>(
        act_src, act_dst, diff, nf, arow, grow, out);

    // 4) cost-edge scatter (-beta)
    cost_edges_k<<<NEDGES / 256, 256, 0, stream>>>(
        edge_src, edge_dst, brow, out);
}